// Round 6
// baseline (1139.383 us; speedup 1.0000x reference)
//
#include <hip/hip_runtime.h>

// LSTM: B=512, T=1000, IN=39, H=64, OUT=48, gate order i,f,g,o.
// R9: weights in LDS (allocator-proof), gate-quad layout, split-K waves,
//     2 batch rows per block.
//   R4-R8 lesson: allocator never grants >~172 VGPRs and silently re-streams
//   register weights from L1/L2 (~2100cy/step floor). LDS residency is
//   structural - can't be "spilled away".
//   Layout: whhG[k*64+j] = {W_hh[g*64+j][k] : g=0..3} (float4 over gates).
//   A ds_read_b128 at [k*64+j] is lane-contiguous (conflict-free, no swizzle)
//   and feeds 4 gates x 2 rows = 8 MACs; h[k]/x[i] are uniform b32 broadcasts.
//   Wave w owns k-slice [16w,16w+16) + i-slice [10w,10w+10); all waves
//   compute partials for both rows; wave0/1 reduce+state rows A/B;
//   wave2/3 reduce y (W_out k-slice in regs, 16 floats - grantable) + store
//   + x staging. 2 barriers/step. Grid 256 blocks (rows 2b, 2b+1), 1 blk/CU.

#define BB 512
#define TT 1000
#define INF 39
#define HH 64
#define OUTF 48

typedef float v2f __attribute__((ext_vector_type(2)));

__device__ __forceinline__ float sigf(float v)  { return 1.f / (1.f + __expf(-v)); }
__device__ __forceinline__ float tanhx(float v) { return 2.f / (1.f + __expf(-2.f * v)) - 1.f; }

__global__ __launch_bounds__(256, 1)
void lstm_ldsk(const float* __restrict__ x,      // [B,T,IN]
               const float* __restrict__ W_ih,   // [4H, IN]
               const float* __restrict__ W_hh,   // [4H, H]
               const float* __restrict__ b_ih,   // [4H]
               const float* __restrict__ b_hh,   // [4H]
               const float* __restrict__ W_out,  // [OUT, H]
               const float* __restrict__ b_out,  // [OUT]
               float* __restrict__ out)          // [B,T,OUT]
{
    const int tid = threadIdx.x;
    const int j   = tid & 63;            // lane
    const int w   = tid >> 6;            // wave = k-slice owner
    const int blk = blockIdx.x;          // rows 2blk, 2blk+1

    __shared__ float4 whhG[HH * 64];     // 64 KB  gate-quads of W_hh
    __shared__ float4 wihG[40 * 64];     // 40 KB  gate-quads of W_ih (i=39 zero)
    __shared__ float4 parts[2][4][64];   // 8 KB   gate partials [row][wave][lane]
    __shared__ float  yparts[2][4][64];  // 2 KB   y partials (j<48 used)
    __shared__ __align__(16) float hsb[2][2][HH];  // [parity][row][j]
    __shared__ __align__(16) float xsb[2][2][40];  // [parity][row][i]

    // ---- one-time staging: gate-quad layouts ----
    for (int idx = tid; idx < HH * 64; idx += 256) {
        const int k = idx >> 6, jj = idx & 63;
        whhG[idx] = make_float4(W_hh[(0*HH+jj)*HH + k], W_hh[(1*HH+jj)*HH + k],
                                W_hh[(2*HH+jj)*HH + k], W_hh[(3*HH+jj)*HH + k]);
    }
    for (int idx = tid; idx < 40 * 64; idx += 256) {
        const int i = idx >> 6, jj = idx & 63;
        float4 v = make_float4(0.f, 0.f, 0.f, 0.f);
        if (i < INF)
            v = make_float4(W_ih[(0*HH+jj)*INF + i], W_ih[(1*HH+jj)*INF + i],
                            W_ih[(2*HH+jj)*INF + i], W_ih[(3*HH+jj)*INF + i]);
        wihG[idx] = v;
    }

    // ---- W_out k-slice in registers (16 floats/lane, static-indexed) ----
    float woa[16];
    float bo = 0.f;
    if (j < OUTF) {
        const float4* p = (const float4*)(W_out + j * HH + 16 * w);  // 64B-aligned
#pragma unroll
        for (int q = 0; q < 4; ++q) {
            const float4 v = p[q];
            woa[4*q+0] = v.x; woa[4*q+1] = v.y; woa[4*q+2] = v.z; woa[4*q+3] = v.w;
        }
        bo = b_out[j];
    } else {
#pragma unroll
        for (int k = 0; k < 16; ++k) woa[k] = 0.f;
    }

    const float bg0 = b_ih[0*HH+j] + b_hh[0*HH+j];
    const float bg1 = b_ih[1*HH+j] + b_hh[1*HH+j];
    const float bg2 = b_ih[2*HH+j] + b_hh[2*HH+j];
    const float bg3 = b_ih[3*HH+j] + b_hh[3*HH+j];

    ((float*)hsb)[tid] = 0.f;                       // h_{-1} = 0 (both parities)
    if (tid < 4) xsb[tid >> 1][tid & 1][39] = 0.f;  // pad slot

    const size_t xbA = (size_t)(2*blk) * TT * INF;
    const size_t xbB = xbA + (size_t)TT * INF;
    const size_t obA = (size_t)(2*blk) * TT * OUTF;
    const size_t obB = obA + (size_t)TT * OUTF;

    float xreg = 0.f;
    if (w == 2 && j < INF) { xsb[0][0][j] = x[xbA + j]; xreg = x[xbA + INF + j]; }
    if (w == 3 && j < INF) { xsb[0][1][j] = x[xbB + j]; xreg = x[xbB + INF + j]; }
    float c = 0.f;                        // cell state (wave0: row A, wave1: row B)
    __syncthreads();

    const int kbase = 16 * w;
    const float4* wk = whhG + kbase * 64 + j;       // offsets fold into ds imm
    const float4* wi = wihG + (10 * w) * 64 + j;

    for (int t = 0; t < TT; ++t) {
        const int par = t & 1;
        const float* hA = hsb[par ^ 1][0];          // h_{t-1}
        const float* hB = hsb[par ^ 1][1];
        const float* xA = xsb[par][0];              // x_t
        const float* xB = xsb[par][1];

        v2f aA01 = {0.f,0.f}, aA23 = {0.f,0.f};
        v2f aB01 = {0.f,0.f}, aB23 = {0.f,0.f};
        v2f yv   = {0.f,0.f};                       // {yA, yB} partial

#define HHK(K) { \
        const float4 wg = wk[(K) * 64]; \
        const float ha = hA[kbase + (K)]; \
        const float hb = hB[kbase + (K)]; \
        aA01 += (v2f){wg.x, wg.y} * (v2f){ha, ha}; \
        aA23 += (v2f){wg.z, wg.w} * (v2f){ha, ha}; \
        aB01 += (v2f){wg.x, wg.y} * (v2f){hb, hb}; \
        aB23 += (v2f){wg.z, wg.w} * (v2f){hb, hb}; \
        yv   += (v2f){ha, hb} * (v2f){woa[K], woa[K]}; }
        HHK(0)  HHK(1)  HHK(2)  HHK(3)  HHK(4)  HHK(5)  HHK(6)  HHK(7)
        HHK(8)  HHK(9)  HHK(10) HHK(11) HHK(12) HHK(13) HHK(14) HHK(15)
#undef HHK

#define XIK(I) { \
        const float4 wg = wi[(I) * 64]; \
        const float xa = xA[10*w + (I)]; \
        const float xb = xB[10*w + (I)]; \
        aA01 += (v2f){wg.x, wg.y} * (v2f){xa, xa}; \
        aA23 += (v2f){wg.z, wg.w} * (v2f){xa, xa}; \
        aB01 += (v2f){wg.x, wg.y} * (v2f){xb, xb}; \
        aB23 += (v2f){wg.z, wg.w} * (v2f){xb, xb}; }
        XIK(0) XIK(1) XIK(2) XIK(3) XIK(4) XIK(5) XIK(6) XIK(7) XIK(8) XIK(9)
#undef XIK

        if (w != 0) parts[0][w][j] = make_float4(aA01.x, aA01.y, aA23.x, aA23.y);
        if (w != 1) parts[1][w][j] = make_float4(aB01.x, aB01.y, aB23.x, aB23.y);
        if (w != 2) yparts[0][w][j] = yv.x;
        if (w != 3) yparts[1][w][j] = yv.y;
        __syncthreads();                  // A: partials ready

        if (w == 0) {
            const float4 p1 = parts[0][1][j];
            const float4 p2 = parts[0][2][j];
            const float4 p3 = parts[0][3][j];
            const float gi = aA01.x + p1.x + p2.x + p3.x + bg0;
            const float gf = aA01.y + p1.y + p2.y + p3.y + bg1;
            const float gg = aA23.x + p1.z + p2.z + p3.z + bg2;
            const float go = aA23.y + p1.w + p2.w + p3.w + bg3;
            c = fmaf(sigf(gf), c, sigf(gi) * tanhx(gg));
            hsb[par][0][j] = sigf(go) * tanhx(c);
        } else if (w == 1) {
            const float4 p0 = parts[1][0][j];
            const float4 p2 = parts[1][2][j];
            const float4 p3 = parts[1][3][j];
            const float gi = aB01.x + p0.x + p2.x + p3.x + bg0;
            const float gf = aB01.y + p0.y + p2.y + p3.y + bg1;
            const float gg = aB23.x + p0.z + p2.z + p3.z + bg2;
            const float go = aB23.y + p0.w + p2.w + p3.w + bg3;
            c = fmaf(sigf(gf), c, sigf(gi) * tanhx(gg));
            hsb[par][1][j] = sigf(go) * tanhx(c);
        } else if (w == 2) {
            if (j < INF) {                // stage x_{t+1} row A
                xsb[par ^ 1][0][j] = xreg;
                if (t + 2 < TT) xreg = x[xbA + (size_t)(t + 2) * INF + j];
            }
            if (t >= 1 && j < OUTF) {     // y_{t-1} row A
                const float s = yv.x + yparts[0][0][j] + yparts[0][1][j] + yparts[0][3][j];
                __builtin_nontemporal_store(sigf(s + bo),
                    &out[obA + (size_t)(t - 1) * OUTF + j]);
            }
        } else {
            if (j < INF) {                // stage x_{t+1} row B
                xsb[par ^ 1][1][j] = xreg;
                if (t + 2 < TT) xreg = x[xbB + (size_t)(t + 2) * INF + j];
            }
            if (t >= 1 && j < OUTF) {     // y_{t-1} row B
                const float s = yv.y + yparts[1][0][j] + yparts[1][1][j] + yparts[1][2][j];
                __builtin_nontemporal_store(sigf(s + bo),
                    &out[obB + (size_t)(t - 1) * OUTF + j]);
            }
        }
        __syncthreads();                  // B: hs[par]=h_t, xs[par^1]=x_{t+1}
    }

    // ---- epilogue: y_{T-1} from h_{T-1} (parity (TT-1)&1 = 1) ----
    {
        const float* hA = hsb[1][0];
        const float* hB = hsb[1][1];
        v2f yv = {0.f, 0.f};
#define YK(K) yv += (v2f){hA[kbase + (K)], hB[kbase + (K)]} * (v2f){woa[K], woa[K]};
        YK(0)  YK(1)  YK(2)  YK(3)  YK(4)  YK(5)  YK(6)  YK(7)
        YK(8)  YK(9)  YK(10) YK(11) YK(12) YK(13) YK(14) YK(15)
#undef YK
        if (w != 2) yparts[0][w][j] = yv.x;
        if (w != 3) yparts[1][w][j] = yv.y;
        __syncthreads();
        if (w == 2 && j < OUTF) {
            const float s = yv.x + yparts[0][0][j] + yparts[0][1][j] + yparts[0][3][j];
            __builtin_nontemporal_store(sigf(s + bo),
                &out[obA + (size_t)(TT - 1) * OUTF + j]);
        }
        if (w == 3 && j < OUTF) {
            const float s = yv.y + yparts[1][0][j] + yparts[1][1][j] + yparts[1][2][j];
            __builtin_nontemporal_store(sigf(s + bo),
                &out[obB + (size_t)(TT - 1) * OUTF + j]);
        }
    }
}

extern "C" void kernel_launch(void* const* d_in, const int* in_sizes, int n_in,
                              void* d_out, int out_size, void* d_ws, size_t ws_size,
                              hipStream_t stream) {
    const float* x     = (const float*)d_in[0];
    const float* W_ih  = (const float*)d_in[1];
    const float* W_hh  = (const float*)d_in[2];
    const float* b_ih  = (const float*)d_in[3];
    const float* b_hh  = (const float*)d_in[4];
    const float* W_out = (const float*)d_in[5];
    const float* b_out = (const float*)d_in[6];
    float* out = (float*)d_out;

    lstm_ldsk<<<dim3(BB / 2), dim3(256), 0, stream>>>(
        x, W_ih, W_hh, b_ih, b_hh, W_out, b_out, out);
}

// Round 7
// 879.271 us; speedup vs baseline: 1.2958x; 1.2958x over previous
//
#include <hip/hip_runtime.h>

// LSTM: B=512, T=1000, IN=39, H=64, OUT=48, gate order i,f,g,o.
// R10: ALL weights in registers, one batch row per 256-thread block, grid 512.
//   R9 post-mortem: LDS-weight streaming = ~2450cy/step of LDS instruction
//   slots (26 b128 + 52 b32 per thread). LDS pipe (128B/cy) can't re-stream
//   104KB/step. Register file is the only storage with the bandwidth.
//   Allocator history: grants track the ASK (172 granted at ask~300 under
//   launch_bounds(128,1); 132 granted unasked in R9). This round asks ~145
//   under launch_bounds(256,1): thread (w,j) owns W_hh[{g*64+j}][16w..16w+16)
//   (64f) + W_ih[{g*64+j}][10w..10w+10) (20f) + W_out[j][16w..16w+16) (16f).
//   Per step: ~92 pk-FMA, 7 uniform LDS reads (h:4 b128, x:2 b128+1 b64),
//   1 b128 partial write; wave0 reduces gates+state, wave1 reduces y+stores,
//   wave2 stages x. 2 barriers/step; 2 blocks/CU hide each other's tails.

#define BB 512
#define TT 1000
#define INF 39
#define HH 64
#define OUTF 48

typedef float v2f __attribute__((ext_vector_type(2)));

__device__ __forceinline__ float sigf(float v)  { return 1.f / (1.f + __expf(-v)); }
__device__ __forceinline__ float tanhx(float v) { return 2.f / (1.f + __expf(-2.f * v)) - 1.f; }

#define Q5(M, G)  M(G,0) M(G,1) M(G,2) M(G,3) M(G,4)
#define Q8(M, G)  M(G,0) M(G,1) M(G,2) M(G,3) M(G,4) M(G,5) M(G,6) M(G,7)

__global__ __launch_bounds__(256, 1)
void lstm_regw(const float* __restrict__ x,      // [B,T,IN]
               const float* __restrict__ W_ih,   // [4H, IN]
               const float* __restrict__ W_hh,   // [4H, H]
               const float* __restrict__ b_ih,   // [4H]
               const float* __restrict__ b_hh,   // [4H]
               const float* __restrict__ W_out,  // [OUT, H]
               const float* __restrict__ b_out,  // [OUT]
               float* __restrict__ out)          // [B,T,OUT]
{
    const int tid = threadIdx.x;
    const int j   = tid & 63;            // lane
    const int w   = tid >> 6;            // wave = k-slice owner (0..3)
    const int b   = blockIdx.x;          // one batch row per block

    __shared__ __align__(16) float  hsb[2][HH];    // h double buffer
    __shared__ __align__(16) float  xsb[2][48];    // x_t, 12-stride slices, padded
    __shared__ __align__(16) float4 parts[4][64];  // gate partials [wave][lane]
    __shared__ float                 yp[4][64];    // y partials

    const size_t xb = (size_t)b * TT * INF;
    const size_t ob = (size_t)b * TT * OUTF;

    // ---- weights into named, pinned registers (100 floats/lane) ----
    // W_hh[{g*64+j}][16w..16w+16): 8 v2f per gate
#define LHH(g, q) v2f whh##g##_##q; { \
    const v2f* p_ = (const v2f*)(W_hh + ((g)*HH + j) * HH + 16 * w); \
    whh##g##_##q = p_[q]; } \
    asm volatile("" : "+v"(whh##g##_##q));
    Q8(LHH, 0) Q8(LHH, 1) Q8(LHH, 2) Q8(LHH, 3)

    // W_ih[{g*64+j}][10w..10w+10): 5 v2f per gate (w=3,q=4,y is OOB -> 0)
#define LIH(g, q) v2f wih##g##_##q; { \
    const float* p_ = W_ih + ((g)*HH + j) * INF + 10 * w; \
    wih##g##_##q.x = (10*w + 2*(q)     < INF) ? p_[2*(q)]     : 0.f; \
    wih##g##_##q.y = (10*w + 2*(q) + 1 < INF) ? p_[2*(q) + 1] : 0.f; } \
    asm volatile("" : "+v"(wih##g##_##q));
    Q5(LIH, 0) Q5(LIH, 1) Q5(LIH, 2) Q5(LIH, 3)

    // W_out[j][16w..16w+16) for j<48: 8 v2f
#define LWO(g, q) v2f wo_##q;            // g unused; reuse Q8 shape
#define LWO2(dummy, q) v2f wo_##q = {0.f, 0.f}; \
    if (j < OUTF) { \
        const v2f* p_ = (const v2f*)(W_out + j * HH + 16 * w); \
        wo_##q = p_[q]; } \
    asm volatile("" : "+v"(wo_##q));
    Q8(LWO2, 0)

    const float bg0 = b_ih[0*HH+j] + b_hh[0*HH+j];
    const float bg1 = b_ih[1*HH+j] + b_hh[1*HH+j];
    const float bg2 = b_ih[2*HH+j] + b_hh[2*HH+j];
    const float bg3 = b_ih[3*HH+j] + b_hh[3*HH+j];
    const float bo  = (j < OUTF) ? b_out[j] : 0.f;

    // ---- init LDS ----
    if (tid < 96)  ((float*)xsb)[tid] = 0.f;            // zeros incl. pad slots
    if (tid >= 128) ((float*)hsb)[tid - 128] = 0.f;     // h_{-1} = 0 (both bufs)
    __syncthreads();
    float xreg = 0.f;
    if (w == 2 && j < INF) {
        xsb[0][(j / 10) * 12 + (j % 10)] = x[xb + j];   // x_0
        xreg = x[xb + INF + j];                         // x_1
    }
    float c = 0.f;                                      // cell state (wave 0)
    __syncthreads();

    for (int t = 0; t < TT; ++t) {
        const int par = t & 1;
        // ---- uniform slice reads (h_{t-1}, x_t) ----
        const float4* h4 = (const float4*)(hsb[par ^ 1] + 16 * w);
        const float4 hq0 = h4[0], hq1 = h4[1], hq2 = h4[2], hq3 = h4[3];
        const float4* x4 = (const float4*)(xsb[par] + 12 * w);
        const float4 xq0 = x4[0], xq1 = x4[1];
        const float2 xq2 = *(const float2*)(xsb[par] + 12 * w + 8);

        // ---- gate partials over this wave's k/i slice ----
        float sg0, sg1, sg2, sg3;
#define GDOT(g, OUTV) { \
        v2f aA = {0.f, 0.f}, aB = {0.f, 0.f}; \
        aA += (v2f){hq0.x, hq0.y} * whh##g##_0; \
        aB += (v2f){hq0.z, hq0.w} * whh##g##_1; \
        aA += (v2f){hq1.x, hq1.y} * whh##g##_2; \
        aB += (v2f){hq1.z, hq1.w} * whh##g##_3; \
        aA += (v2f){hq2.x, hq2.y} * whh##g##_4; \
        aB += (v2f){hq2.z, hq2.w} * whh##g##_5; \
        aA += (v2f){hq3.x, hq3.y} * whh##g##_6; \
        aB += (v2f){hq3.z, hq3.w} * whh##g##_7; \
        aA += (v2f){xq0.x, xq0.y} * wih##g##_0; \
        aB += (v2f){xq0.z, xq0.w} * wih##g##_1; \
        aA += (v2f){xq1.x, xq1.y} * wih##g##_2; \
        aB += (v2f){xq1.z, xq1.w} * wih##g##_3; \
        aA += (v2f){xq2.x, xq2.y} * wih##g##_4; \
        OUTV = (aA.x + aA.y) + (aB.x + aB.y); }
        GDOT(0, sg0) GDOT(1, sg1) GDOT(2, sg2) GDOT(3, sg3)
#undef GDOT

        // y partial for y_{t-1} (h_{t-1} . W_out slice)
        float yv;
        {
            v2f yA = {0.f, 0.f}, yB = {0.f, 0.f};
            yA += (v2f){hq0.x, hq0.y} * wo_0;
            yB += (v2f){hq0.z, hq0.w} * wo_1;
            yA += (v2f){hq1.x, hq1.y} * wo_2;
            yB += (v2f){hq1.z, hq1.w} * wo_3;
            yA += (v2f){hq2.x, hq2.y} * wo_4;
            yB += (v2f){hq2.z, hq2.w} * wo_5;
            yA += (v2f){hq3.x, hq3.y} * wo_6;
            yB += (v2f){hq3.z, hq3.w} * wo_7;
            yv = (yA.x + yA.y) + (yB.x + yB.y);
        }

        if (w != 0) parts[w][j] = make_float4(sg0, sg1, sg2, sg3);
        if (w != 1) yp[w][j] = yv;
        __syncthreads();                  // A: partials ready; slice reads done

        if (w == 0) {
            const float4 p1 = parts[1][j];
            const float4 p2 = parts[2][j];
            const float4 p3 = parts[3][j];
            const float gi = sg0 + p1.x + p2.x + p3.x + bg0;
            const float gf = sg1 + p1.y + p2.y + p3.y + bg1;
            const float gg = sg2 + p1.z + p2.z + p3.z + bg2;
            const float go = sg3 + p1.w + p2.w + p3.w + bg3;
            c = fmaf(sigf(gf), c, sigf(gi) * tanhx(gg));
            hsb[par][j] = sigf(go) * tanhx(c);
        } else if (w == 1) {
            if (t >= 1 && j < OUTF) {
                const float s = yv + yp[0][j] + yp[2][j] + yp[3][j] + bo;
                __builtin_nontemporal_store(sigf(s),
                    &out[ob + (size_t)(t - 1) * OUTF + j]);
            }
        } else if (w == 2) {
            if (j < INF) {                // stage x_{t+1}; prefetch x_{t+2}
                xsb[par ^ 1][(j / 10) * 12 + (j % 10)] = xreg;
                if (t + 2 < TT) xreg = x[xb + (size_t)(t + 2) * INF + j];
            }
        }
        __syncthreads();                  // B: hsb[par]=h_t, xsb[par^1]=x_{t+1}
    }

    // ---- epilogue: y_{T-1} from h_{T-1} (in hsb[(TT-1)&1] = hsb[1]) ----
    {
        const float4* h4 = (const float4*)(hsb[1] + 16 * w);
        const float4 hq0 = h4[0], hq1 = h4[1], hq2 = h4[2], hq3 = h4[3];
        v2f yA = {0.f, 0.f}, yB = {0.f, 0.f};
        yA += (v2f){hq0.x, hq0.y} * wo_0;
        yB += (v2f){hq0.z, hq0.w} * wo_1;
        yA += (v2f){hq1.x, hq1.y} * wo_2;
        yB += (v2f){hq1.z, hq1.w} * wo_3;
        yA += (v2f){hq2.x, hq2.y} * wo_4;
        yB += (v2f){hq2.z, hq2.w} * wo_5;
        yA += (v2f){hq3.x, hq3.y} * wo_6;
        yB += (v2f){hq3.z, hq3.w} * wo_7;
        const float yv = (yA.x + yA.y) + (yB.x + yB.y);
        if (w != 1) yp[w][j] = yv;
        __syncthreads();
        if (w == 1 && j < OUTF) {
            const float s = yv + yp[0][j] + yp[2][j] + yp[3][j] + bo;
            __builtin_nontemporal_store(sigf(s),
                &out[ob + (size_t)(TT - 1) * OUTF + j]);
        }
    }
}

extern "C" void kernel_launch(void* const* d_in, const int* in_sizes, int n_in,
                              void* d_out, int out_size, void* d_ws, size_t ws_size,
                              hipStream_t stream) {
    const float* x     = (const float*)d_in[0];
    const float* W_ih  = (const float*)d_in[1];
    const float* W_hh  = (const float*)d_in[2];
    const float* b_ih  = (const float*)d_in[3];
    const float* b_hh  = (const float*)d_in[4];
    const float* W_out = (const float*)d_in[5];
    const float* b_out = (const float*)d_in[6];
    float* out = (float*)d_out;

    lstm_regw<<<dim3(BB), dim3(256), 0, stream>>>(
        x, W_ih, W_hh, b_ih, b_hh, W_out, b_out, out);
}